// Round 11
// baseline (187.186 us; speedup 1.0000x reference)
//
#include <hip/hip_runtime.h>
#include <hip/hip_bf16.h>

#define NN       100000    // nodes
#define NE       1600000   // edges
#define IN_F     256
#define HID      64
#define NC       40
#define CAP      64        // fixed CSR slots/node; P(in-deg > 64) ~ 1e-19 for Poisson(16)
#define NBKT     391       // node buckets: bucket = id >> 8 (256 nodes each)
#define NBP1     500       // partition blocks; EPB edges each
#define EPB      3200      // NE / NBP1 (exact)
#define EI4      800       // EPB / 4 (int4 loads)
#define NB_GEMM  1563      // ceil(NN/64)

typedef __attribute__((ext_vector_type(8))) short bf16x8;
typedef __attribute__((ext_vector_type(4))) float f32x4;

__device__ __forceinline__ unsigned short f2bf(float x) {
    unsigned int u = __builtin_bit_cast(unsigned int, x);
    u += 0x7FFFu + ((u >> 16) & 1u);           // RNE (inputs finite)
    return (unsigned short)(u >> 16);
}
__device__ __forceinline__ float bf2f(unsigned short h) {
    unsigned int u = ((unsigned int)h) << 16;
    return __builtin_bit_cast(float, u);
}

// ---------------- count + packW1 + packW2 (merged) ----------------------------
__global__ __launch_bounds__(256) void k_count(const int* __restrict__ src,
                                               const int* __restrict__ dst,
                                               const float* __restrict__ W1,
                                               const float* __restrict__ W2,
                                               unsigned short* __restrict__ Bp,
                                               unsigned short* __restrict__ Bp2,
                                               int* __restrict__ gcnt) {
    __shared__ int sh[2 * NBKT];              // [0,NBKT)=dst, [NBKT,2*NBKT)=src
    const int cb = blockIdx.x, t = threadIdx.x;
    if (cb >= NBP1 + 8) {
        // ---- W2 -> bf16 B-frags: 6 frags (kt*3+nt), cols >= 40 zeroed ----
        const int tid = (cb - NBP1 - 8) * 256 + t;
        if (tid >= 6 * 64) return;
        const int lane = tid & 63, f = tid >> 6;
        const int nt = f % 3, kt = f / 3;
        const int col = nt * 16 + (lane & 15);
        const int kb  = kt * 32 + (lane >> 4) * 8;
        unsigned short o[8];
        #pragma unroll
        for (int j = 0; j < 8; ++j)
            o[j] = (col < NC) ? f2bf(W2[(kb + j) * NC + col]) : (unsigned short)0;
        #pragma unroll
        for (int j = 0; j < 8; ++j) Bp2[tid * 8 + j] = o[j];
        return;
    }
    if (cb >= NBP1) {
        // ---- W1 -> bf16 B-fragment pre-pack (8 blocks, 2048 threads) ----
        const int tid = (cb - NBP1) * 256 + t;        // < 8*4*64 exactly
        const int lane = tid & 63, nt = (tid >> 6) & 3, kt = tid >> 8;
        const int col = nt * 16 + (lane & 15);
        const int kb  = kt * 32 + (lane >> 4) * 8;
        unsigned short o[8];
        #pragma unroll
        for (int j = 0; j < 8; ++j) o[j] = f2bf(W1[(kb + j) * HID + col]);
        #pragma unroll
        for (int j = 0; j < 8; ++j) Bp[tid * 8 + j] = o[j];
        return;
    }
    for (int j = t; j < 2 * NBKT; j += 256) sh[j] = 0;
    __syncthreads();
    const int4* s4 = reinterpret_cast<const int4*>(src) + (size_t)cb * EI4;
    const int4* d4 = reinterpret_cast<const int4*>(dst) + (size_t)cb * EI4;
    for (int i = t; i < EI4; i += 256) {
        const int4 d = d4[i], s = s4[i];
        atomicAdd(&sh[d.x >> 8], 1);
        atomicAdd(&sh[d.y >> 8], 1);
        atomicAdd(&sh[d.z >> 8], 1);
        atomicAdd(&sh[d.w >> 8], 1);
        atomicAdd(&sh[NBKT + (s.x >> 8)], 1);
        atomicAdd(&sh[NBKT + (s.y >> 8)], 1);
        atomicAdd(&sh[NBKT + (s.z >> 8)], 1);
        atomicAdd(&sh[NBKT + (s.w >> 8)], 1);
    }
    __syncthreads();
    for (int k = t; k < 2 * NBKT; k += 256) gcnt[k * NBP1 + cb] = sh[k];
}

// ---------------- GEMM1: deep-staged bf16 LDS tile + MFMA ---------------------
__global__ __launch_bounds__(256) void k_gemm1(const float* __restrict__ X,
                                               const unsigned short* __restrict__ Bp,
                                               const float* __restrict__ nsrcf,
                                               unsigned short* __restrict__ h1b) {
    __shared__ unsigned short xt[64 * 256];   // 32 KB bf16 tile (XOR-swizzled)
    const int bid = blockIdx.x, t = threadIdx.x;
    const int r0 = bid * 64;

    f32x4 v[16];
    #pragma unroll
    for (int q = 0; q < 16; ++q) {
        const int idx = q * 1024 + t * 4;             // element index in 64x256 tile
        const int row = idx >> 8, col = idx & 255;
        const int gr  = (r0 + row < NN) ? (r0 + row) : (NN - 1);   // tail clamp
        v[q] = *reinterpret_cast<const f32x4*>(X + (size_t)gr * IN_F + col);
    }
    __builtin_amdgcn_sched_barrier(0);                // keep all 16 in flight
    #pragma unroll
    for (int q = 0; q < 16; ++q) {
        const int idx = q * 1024 + t * 4;
        const int row = idx >> 8, col = idx & 255;
        const unsigned int w0 = (unsigned)f2bf(v[q][0]) | ((unsigned)f2bf(v[q][1]) << 16);
        const unsigned int w1 = (unsigned)f2bf(v[q][2]) | ((unsigned)f2bf(v[q][3]) << 16);
        const int a = ((row * 256 + col) * 2) ^ ((row & 7) << 4);  // byte addr, swizzled
        uint2 pk; pk.x = w0; pk.y = w1;
        *reinterpret_cast<uint2*>(reinterpret_cast<char*>(xt) + a) = pk;
    }
    __syncthreads();
    const int lane = t & 63;
    const int wid  = t >> 6;
    const int rloc = wid * 16 + (lane & 15);          // local row 0..63
    const bf16x8* bp = reinterpret_cast<const bf16x8*>(Bp) + lane;

    f32x4 acc0 = {0.f, 0.f, 0.f, 0.f};
    f32x4 acc1 = {0.f, 0.f, 0.f, 0.f};
    f32x4 acc2 = {0.f, 0.f, 0.f, 0.f};
    f32x4 acc3 = {0.f, 0.f, 0.f, 0.f};

    #pragma unroll
    for (int kt = 0; kt < 8; ++kt) {
        const int koff = (lane >> 4) * 8 + kt * 32;
        const int a = ((rloc * 256 + koff) * 2) ^ ((rloc & 7) << 4);
        const bf16x8 av = *reinterpret_cast<const bf16x8*>(
                              reinterpret_cast<char*>(xt) + a);
        const bf16x8 b0 = bp[(kt * 4 + 0) * 64];
        const bf16x8 b1 = bp[(kt * 4 + 1) * 64];
        const bf16x8 b2 = bp[(kt * 4 + 2) * 64];
        const bf16x8 b3 = bp[(kt * 4 + 3) * 64];
        acc0 = __builtin_amdgcn_mfma_f32_16x16x32_bf16(av, b0, acc0, 0, 0, 0);
        acc1 = __builtin_amdgcn_mfma_f32_16x16x32_bf16(av, b1, acc1, 0, 0, 0);
        acc2 = __builtin_amdgcn_mfma_f32_16x16x32_bf16(av, b2, acc2, 0, 0, 0);
        acc3 = __builtin_amdgcn_mfma_f32_16x16x32_bf16(av, b3, acc3, 0, 0, 0);
    }

    // C/D layout: col = lane&15, row = (lane>>4)*4 + reg   [m89-verified]
    const int crow = r0 + wid * 16 + (lane >> 4) * 4;
    const int ccol = lane & 15;
    #pragma unroll
    for (int rr = 0; rr < 4; ++rr) {
        const int orow = crow + rr;
        if (orow < NN) {
            const float ns = nsrcf[orow];
            unsigned short* o = h1b + (size_t)orow * HID + ccol;
            o[0]  = f2bf(acc0[rr] * ns);
            o[16] = f2bf(acc1[rr] * ns);
            o[32] = f2bf(acc2[rr] * ns);
            o[48] = f2bf(acc3[rr] * ns);
        }
    }
}

// ---------------- scan A: per-row total = sum over blocks --------------------
__global__ __launch_bounds__(256) void k_scanA(const int* __restrict__ gcnt,
                                               int* __restrict__ bsum) {
    __shared__ int red[256];
    const int r = blockIdx.x, t = threadIdx.x;
    int x = gcnt[r * NBP1 + t];
    if (256 + t < NBP1) x += gcnt[r * NBP1 + 256 + t];
    red[t] = x;
    __syncthreads();
    for (int off = 128; off > 0; off >>= 1) {
        if (t < off) red[t] += red[t + off];
        __syncthreads();
    }
    if (t == 0) bsum[r] = red[0];
}

// ---------------- scan B: per-array exclusive scan -> bstart[a][0..NBKT] ------
__global__ __launch_bounds__(512) void k_scanB(const int* __restrict__ bsum,
                                               int* __restrict__ bstart) {
    __shared__ int sa[512], sb[512];
    const int a = blockIdx.x, t = threadIdx.x;       // a in {0,1}
    const int x = (t < NBKT) ? bsum[a * NBKT + t] : 0;
    sa[t] = x;
    __syncthreads();
    int* pin = sa; int* pout = sb;
    for (int off = 1; off < 512; off <<= 1) {
        int v = pin[t];
        if (t >= off) v += pin[t - off];
        pout[t] = v;
        __syncthreads();
        int* tmp = pin; pin = pout; pout = tmp;
    }
    if (t <= NBKT) bstart[a * (NBKT + 1) + t] = pin[t] - x;   // exclusive
}

// ---------------- scan C: per-row exclusive scan -> segment bases (in place) --
__global__ __launch_bounds__(512) void k_scanC(int* __restrict__ gcnt,
                                               const int* __restrict__ bstart) {
    __shared__ int sa[512], sb[512];
    const int r = blockIdx.x, t = threadIdx.x;
    const int a = r / NBKT;                           // bstart row offset: r + a
    const int x = (t < NBP1) ? gcnt[r * NBP1 + t] : 0;
    sa[t] = x;
    __syncthreads();
    int* pin = sa; int* pout = sb;
    for (int off = 1; off < 512; off <<= 1) {
        int v = pin[t];
        if (t >= off) v += pin[t - off];
        pout[t] = v;
        __syncthreads();
        int* tmp = pin; pin = pout; pout = tmp;
    }
    if (t < NBP1) gcnt[r * NBP1 + t] = bstart[r + a] + pin[t] - x;
}

// ---------------- partition pass b: scatter into dst- AND src-bucket segments -
__global__ __launch_bounds__(256) void k_scatter(const int* __restrict__ src,
                                                 const int* __restrict__ dst,
                                                 const int* __restrict__ gbase,
                                                 int* __restrict__ pedge,
                                                 unsigned char* __restrict__ psrc) {
    __shared__ int cur[2 * NBKT];
    const int b = blockIdx.x, t = threadIdx.x;
    for (int k = t; k < 2 * NBKT; k += 256) cur[k] = gbase[k * NBP1 + b];
    __syncthreads();
    const int4* s4 = reinterpret_cast<const int4*>(src) + (size_t)b * EI4;
    const int4* d4 = reinterpret_cast<const int4*>(dst) + (size_t)b * EI4;
    for (int i = t; i < EI4; i += 256) {
        const int4 dd = d4[i], ss = s4[i];
        {
            const int posD = atomicAdd(&cur[dd.x >> 8], 1);
            pedge[posD] = ss.x | ((dd.x & 255) << 17);
            const int posS = atomicAdd(&cur[NBKT + (ss.x >> 8)], 1);
            psrc[posS] = (unsigned char)(ss.x & 255);
        }
        {
            const int posD = atomicAdd(&cur[dd.y >> 8], 1);
            pedge[posD] = ss.y | ((dd.y & 255) << 17);
            const int posS = atomicAdd(&cur[NBKT + (ss.y >> 8)], 1);
            psrc[posS] = (unsigned char)(ss.y & 255);
        }
        {
            const int posD = atomicAdd(&cur[dd.z >> 8], 1);
            pedge[posD] = ss.z | ((dd.z & 255) << 17);
            const int posS = atomicAdd(&cur[NBKT + (ss.z >> 8)], 1);
            psrc[posS] = (unsigned char)(ss.z & 255);
        }
        {
            const int posD = atomicAdd(&cur[dd.w >> 8], 1);
            pedge[posD] = ss.w | ((dd.w & 255) << 17);
            const int posS = atomicAdd(&cur[NBKT + (ss.w >> 8)], 1);
            psrc[posS] = (unsigned char)(ss.w & 255);
        }
    }
}

// ---------------- place (merged D+S): CSR slots + ideg | src counts -> nsrcf --
__global__ __launch_bounds__(256) void k_place(const int* __restrict__ pedge,
                                               const unsigned char* __restrict__ psrc,
                                               const int* __restrict__ bstart,
                                               int* __restrict__ eidx,
                                               int* __restrict__ ideg,
                                               float* __restrict__ nsrcf) {
    __shared__ int cnt[256];
    const int kk = blockIdx.x, t = threadIdx.x;
    cnt[t] = 0;
    __syncthreads();
    if (kk < NBKT) {
        const int k  = kk;
        const int i0 = bstart[k], i1 = bstart[k + 1];
        for (int i = i0 + t; i < i1; i += 256) {
            const int v  = pedge[i];
            const int s  = v & 0x1FFFF;
            const int lo = v >> 17;
            const int c  = atomicAdd(&cnt[lo], 1);            // LDS atomic
            if (c < CAP) eidx[(size_t)((k << 8) | lo) * CAP + c] = s;
        }
        __syncthreads();
        const int d = (k << 8) | t;
        if (d < NN) ideg[d] = cnt[t];
    } else {
        const int k  = kk - NBKT;
        const int* bs = bstart + (NBKT + 1);
        const int i0 = bs[k], i1 = bs[k + 1];
        for (int i = i0 + t; i < i1; i += 256)
            atomicAdd(&cnt[psrc[i]], 1);                      // LDS atomic
        __syncthreads();
        const int d = (k << 8) | t;
        if (d < NN) nsrcf[d] = rsqrtf(fmaxf((float)cnt[t], 1.f));
    }
}

// ---------------- aggregation, 64 feats: clamped 16-edge window ---------------
// r11: tail loops eliminated. Every iteration issues 8 pair-gathers (16 edges)
// in flight; out-of-range edges clamp their (scalar) slot to m-1 — re-gather
// of an L1-hot line, masked out of the sum via 0/1 fmaf. Poisson(16) degrees
// -> most nodes complete in ONE full-depth round (r8's unroll-16 regressed
// precisely because short-degree nodes fell into the serial 2-edge tail).
__global__ __launch_bounds__(256) void k_agg64(const int* __restrict__ eidx,
                                               const int* __restrict__ ideg,
                                               const unsigned short* __restrict__ h1b,
                                               const float* __restrict__ b1,
                                               float* __restrict__ hout) {
    const int w    = (blockIdx.x * 256 + threadIdx.x) >> 6;
    const int lane = threadIdx.x & 63;
    if (w >= NN) return;
    const int cnt  = ideg[w];
    const int m    = cnt < CAP ? cnt : CAP;
    const int idxv = eidx[(size_t)w * CAP + lane];   // slots >= m: garbage, never read
    const bool hi  = lane >= 32;
    const unsigned fofs = (unsigned)(lane & 31) * 4u;   // feature-pair byte offset
    const char* hb = reinterpret_cast<const char*>(h1b);
    float ax = 0.f, ay = 0.f;
    for (int j = 0; j < m; j += 16) {
        unsigned int vv[8];
        float mk[8];
        #pragma unroll
        for (int u = 0; u < 8; ++u) {
            const int eA = j + 2 * u, eB = eA + 1;
            const int cA = (eA < m) ? eA : (m - 1);  // scalar clamp
            const int cB = (eB < m) ? eB : (m - 1);
            const int sA = __builtin_amdgcn_readlane(idxv, cA);
            const int sB = __builtin_amdgcn_readlane(idxv, cB);
            const unsigned ofs = (unsigned)(hi ? sB : sA) * 128u + fofs;
            vv[u] = *reinterpret_cast<const unsigned int*>(hb + ofs);
            mk[u] = ((hi ? eB : eA) < m) ? 1.f : 0.f;
        }
        #pragma unroll
        for (int u = 0; u < 8; ++u) {
            ax = fmaf(bf2f((unsigned short)(vv[u] & 0xffffu)), mk[u], ax);
            ay = fmaf(bf2f((unsigned short)(vv[u] >> 16)), mk[u], ay);
        }
    }
    ax += __shfl(ax, lane ^ 32);                     // combine halves
    ay += __shfl(ay, lane ^ 32);
    if (lane < 32) {
        const float nd = rsqrtf(fmaxf((float)cnt, 1.f));
        const float2 bb = *reinterpret_cast<const float2*>(b1 + (lane & 31) * 2);
        float2 o;
        o.x = fmaf(ax, nd, bb.x);
        o.y = fmaf(ay, nd, bb.y);
        *reinterpret_cast<float2*>(hout + (size_t)w * HID + (lane & 31) * 2) = o;
    }
}

// ---------------- layer 2 GEMM via MFMA: relu(h) @ W2 -------------------------
__global__ __launch_bounds__(256) void k_gemm2(const float* __restrict__ h,
                                               const unsigned short* __restrict__ Bp2,
                                               const float* __restrict__ nsrcf,
                                               unsigned short* __restrict__ xwb) {
    const int t = threadIdx.x;
    const int lane = t & 63;
    const int wid  = t >> 6;
    const int r0w  = blockIdx.x * 64 + wid * 16;
    if (r0w >= NN) return;                            // NN % 16 == 0: no row tail
    const int row = r0w + (lane & 15);
    const float* hr = h + (size_t)row * HID + (lane >> 4) * 8;
    const bf16x8* bp = reinterpret_cast<const bf16x8*>(Bp2) + lane;

    f32x4 acc0 = {0.f, 0.f, 0.f, 0.f};
    f32x4 acc1 = {0.f, 0.f, 0.f, 0.f};
    f32x4 acc2 = {0.f, 0.f, 0.f, 0.f};
    #pragma unroll
    for (int kt = 0; kt < 2; ++kt) {
        const f32x4 v0 = *reinterpret_cast<const f32x4*>(hr + kt * 32);
        const f32x4 v1 = *reinterpret_cast<const f32x4*>(hr + kt * 32 + 4);
        bf16x8 a;
        a[0] = (short)f2bf(fmaxf(v0[0], 0.f));
        a[1] = (short)f2bf(fmaxf(v0[1], 0.f));
        a[2] = (short)f2bf(fmaxf(v0[2], 0.f));
        a[3] = (short)f2bf(fmaxf(v0[3], 0.f));
        a[4] = (short)f2bf(fmaxf(v1[0], 0.f));
        a[5] = (short)f2bf(fmaxf(v1[1], 0.f));
        a[6] = (short)f2bf(fmaxf(v1[2], 0.f));
        a[7] = (short)f2bf(fmaxf(v1[3], 0.f));
        const bf16x8 b0 = bp[(kt * 3 + 0) * 64];
        const bf16x8 b1 = bp[(kt * 3 + 1) * 64];
        const bf16x8 b2 = bp[(kt * 3 + 2) * 64];
        acc0 = __builtin_amdgcn_mfma_f32_16x16x32_bf16(a, b0, acc0, 0, 0, 0);
        acc1 = __builtin_amdgcn_mfma_f32_16x16x32_bf16(a, b1, acc1, 0, 0, 0);
        acc2 = __builtin_amdgcn_mfma_f32_16x16x32_bf16(a, b2, acc2, 0, 0, 0);
    }
    // C/D layout: col = lane&15, row = (lane>>4)*4 + reg
    const int crow = r0w + (lane >> 4) * 4;
    const int ccol = lane & 15;
    #pragma unroll
    for (int rr = 0; rr < 4; ++rr) {
        const int orow = crow + rr;
        const float ns = nsrcf[orow];
        unsigned short* o = xwb + (size_t)orow * 64 + ccol;
        o[0]  = f2bf(acc0[rr] * ns);
        o[16] = f2bf(acc1[rr] * ns);
        o[32] = f2bf(acc2[rr] * ns);                  // cols 40-47: 0 (zero B-frag)
        o[48] = 0;                                    // pad cols 48-63
    }
}

// ---------------- aggregation, 40 feats: clamped 16-edge window ---------------
__global__ __launch_bounds__(256) void k_agg40(const int* __restrict__ eidx,
                                               const int* __restrict__ ideg,
                                               const unsigned short* __restrict__ xwb,
                                               const float* __restrict__ b2,
                                               float* __restrict__ out) {
    const int w    = (blockIdx.x * 256 + threadIdx.x) >> 6;
    const int lane = threadIdx.x & 63;
    if (w >= NN) return;
    const int cnt  = ideg[w];
    const int m    = cnt < CAP ? cnt : CAP;
    const int idxv = eidx[(size_t)w * CAP + lane];
    const bool hi  = lane >= 32;
    const int  fl  = lane & 31;                      // pair idx; rows padded -> no clamp
    const unsigned fofs = (unsigned)fl * 4u;         // 0..124, inside 128B row
    const char* xb = reinterpret_cast<const char*>(xwb);
    float ax = 0.f, ay = 0.f;
    for (int j = 0; j < m; j += 16) {
        unsigned int vv[8];
        float mk[8];
        #pragma unroll
        for (int u = 0; u < 8; ++u) {
            const int eA = j + 2 * u, eB = eA + 1;
            const int cA = (eA < m) ? eA : (m - 1);
            const int cB = (eB < m) ? eB : (m - 1);
            const int sA = __builtin_amdgcn_readlane(idxv, cA);
            const int sB = __builtin_amdgcn_readlane(idxv, cB);
            const unsigned ofs = (unsigned)(hi ? sB : sA) * 128u + fofs;
            vv[u] = *reinterpret_cast<const unsigned int*>(xb + ofs);
            mk[u] = ((hi ? eB : eA) < m) ? 1.f : 0.f;
        }
        #pragma unroll
        for (int u = 0; u < 8; ++u) {
            ax = fmaf(bf2f((unsigned short)(vv[u] & 0xffffu)), mk[u], ax);
            ay = fmaf(bf2f((unsigned short)(vv[u] >> 16)), mk[u], ay);
        }
    }
    ax += __shfl(ax, lane ^ 32);
    ay += __shfl(ay, lane ^ 32);
    if (lane < 20) {
        const float nd = rsqrtf(fmaxf((float)cnt, 1.f));
        const float2 bb = *reinterpret_cast<const float2*>(b2 + fl * 2);
        float2 o;
        o.x = fmaf(ax, nd, bb.x);
        o.y = fmaf(ay, nd, bb.y);
        *reinterpret_cast<float2*>(out + (size_t)w * NC + fl * 2) = o;
    }
}

extern "C" void kernel_launch(void* const* d_in, const int* in_sizes, int n_in,
                              void* d_out, int out_size, void* d_ws, size_t ws_size,
                              hipStream_t stream) {
    const float* X   = (const float*)d_in[0];
    const int*   src = (const int*)d_in[1];
    const int*   dst = (const int*)d_in[2];
    const float* W1  = (const float*)d_in[3];
    const float* b1  = (const float*)d_in[4];
    const float* W2  = (const float*)d_in[5];
    const float* b2  = (const float*)d_in[6];

    float* out  = (float*)d_out;
    float* xout = out;                          // [NN*NC] final layer-2 output
    float* hout = out + (size_t)NN * NC;        // [NN*HID] layer-1 output h

    // ---- scratch living in d_out (liveness-checked):
    // gcnt/bsum/bstart in xout region (~1.6MB of 16MB): dead before k_agg40 writes xout.
    // pedge+psrc in hout region (8MB of 25.6MB): dead before k_agg64 writes hout.
    int* gcnt   = (int*)xout;                   // [2*NBKT*NBP1] counts -> bases (in-place)
    int* bsum   = gcnt + 2 * NBKT * NBP1;       // [2*NBKT]
    int* bstart = bsum + 2 * NBKT;              // [2*(NBKT+1)]
    int* pedge  = (int*)hout;                   // [NE] packed (src | dlow<<17)
    unsigned char* psrc = (unsigned char*)(pedge + NE);   // [NE] low byte of src

    // ---- workspace layout ----
    char* ws = (char*)d_ws;
    int* ideg  = (int*)ws;                            ws += sizeof(int) * NN;
    int* eidx  = (int*)ws;                            ws += sizeof(int) * (size_t)NN * CAP;
    unsigned short* Bp  = (unsigned short*)ws;        ws += sizeof(unsigned short) * 8 * 4 * 64 * 8;
    unsigned short* Bp2 = (unsigned short*)ws;        ws += sizeof(unsigned short) * 6 * 64 * 8;
    float* nsrcf = (float*)ws;                        ws += sizeof(float) * NN;
    unsigned short* h1b = (unsigned short*)ws;        // [NN*HID] bf16, 12.8 MB
    unsigned short* xwb = h1b;                        // reuse: [NN*64] padded, same 12.8 MB

    // sort pipeline first (produces nsrcf for gemm1's pre-scaled epilogue)
    k_count  <<<NBP1 + 10, 256, 0, stream>>>(src, dst, W1, W2, Bp, Bp2, gcnt);
    k_scanA  <<<2 * NBKT, 256, 0, stream>>>(gcnt, bsum);
    k_scanB  <<<2, 512, 0, stream>>>(bsum, bstart);
    k_scanC  <<<2 * NBKT, 512, 0, stream>>>(gcnt, bstart);
    k_scatter<<<NBP1, 256, 0, stream>>>(src, dst, gcnt, pedge, psrc);
    k_place  <<<2 * NBKT, 256, 0, stream>>>(pedge, psrc, bstart, eidx, ideg, nsrcf);
    k_gemm1  <<<NB_GEMM, 256, 0, stream>>>(X, Bp, nsrcf, h1b);
    k_agg64  <<<(NN * 64 + 255) / 256, 256, 0, stream>>>(eidx, ideg, h1b, b1, hout);
    k_gemm2  <<<NB_GEMM, 256, 0, stream>>>(hout, Bp2, nsrcf, xwb);
    k_agg40  <<<(NN * 64 + 255) / 256, 256, 0, stream>>>(eidx, ideg, xwb, b2, xout);
}

// Round 12
// 173.455 us; speedup vs baseline: 1.0792x; 1.0792x over previous
//
#include <hip/hip_runtime.h>
#include <hip/hip_bf16.h>

#define NN       100000    // nodes
#define NE       1600000   // edges
#define IN_F     256
#define HID      64
#define NC       40
#define CAP      64        // fixed CSR slots/node; P(in-deg > 64) ~ 1e-19 for Poisson(16)
#define NBKT     391       // node buckets: bucket = id >> 8 (256 nodes each)
#define NBP1     500       // partition blocks; EPB edges each
#define EPB      3200      // NE / NBP1 (exact)
#define EI4      800       // EPB / 4 (int4 loads)
#define NB_GEMM  1563      // ceil(NN/64)

typedef __attribute__((ext_vector_type(8))) short bf16x8;
typedef __attribute__((ext_vector_type(4))) float f32x4;

__device__ __forceinline__ unsigned short f2bf(float x) {
    unsigned int u = __builtin_bit_cast(unsigned int, x);
    u += 0x7FFFu + ((u >> 16) & 1u);           // RNE (inputs finite)
    return (unsigned short)(u >> 16);
}
__device__ __forceinline__ float bf2f(unsigned short h) {
    unsigned int u = ((unsigned int)h) << 16;
    return __builtin_bit_cast(float, u);
}

// ---------------- count + packW1 + packW2 (merged) ----------------------------
__global__ __launch_bounds__(256) void k_count(const int* __restrict__ src,
                                               const int* __restrict__ dst,
                                               const float* __restrict__ W1,
                                               const float* __restrict__ W2,
                                               unsigned short* __restrict__ Bp,
                                               unsigned short* __restrict__ Bp2,
                                               int* __restrict__ gcnt) {
    __shared__ int sh[2 * NBKT];              // [0,NBKT)=dst, [NBKT,2*NBKT)=src
    const int cb = blockIdx.x, t = threadIdx.x;
    if (cb >= NBP1 + 8) {
        // ---- W2 -> bf16 B-frags: 6 frags (kt*3+nt), cols >= 40 zeroed ----
        const int tid = (cb - NBP1 - 8) * 256 + t;
        if (tid >= 6 * 64) return;
        const int lane = tid & 63, f = tid >> 6;
        const int nt = f % 3, kt = f / 3;
        const int col = nt * 16 + (lane & 15);
        const int kb  = kt * 32 + (lane >> 4) * 8;
        unsigned short o[8];
        #pragma unroll
        for (int j = 0; j < 8; ++j)
            o[j] = (col < NC) ? f2bf(W2[(kb + j) * NC + col]) : (unsigned short)0;
        #pragma unroll
        for (int j = 0; j < 8; ++j) Bp2[tid * 8 + j] = o[j];
        return;
    }
    if (cb >= NBP1) {
        // ---- W1 -> bf16 B-fragment pre-pack (8 blocks, 2048 threads) ----
        const int tid = (cb - NBP1) * 256 + t;        // < 8*4*64 exactly
        const int lane = tid & 63, nt = (tid >> 6) & 3, kt = tid >> 8;
        const int col = nt * 16 + (lane & 15);
        const int kb  = kt * 32 + (lane >> 4) * 8;
        unsigned short o[8];
        #pragma unroll
        for (int j = 0; j < 8; ++j) o[j] = f2bf(W1[(kb + j) * HID + col]);
        #pragma unroll
        for (int j = 0; j < 8; ++j) Bp[tid * 8 + j] = o[j];
        return;
    }
    for (int j = t; j < 2 * NBKT; j += 256) sh[j] = 0;
    __syncthreads();
    const int4* s4 = reinterpret_cast<const int4*>(src) + (size_t)cb * EI4;
    const int4* d4 = reinterpret_cast<const int4*>(dst) + (size_t)cb * EI4;
    for (int i = t; i < EI4; i += 256) {
        const int4 d = d4[i], s = s4[i];
        atomicAdd(&sh[d.x >> 8], 1);
        atomicAdd(&sh[d.y >> 8], 1);
        atomicAdd(&sh[d.z >> 8], 1);
        atomicAdd(&sh[d.w >> 8], 1);
        atomicAdd(&sh[NBKT + (s.x >> 8)], 1);
        atomicAdd(&sh[NBKT + (s.y >> 8)], 1);
        atomicAdd(&sh[NBKT + (s.z >> 8)], 1);
        atomicAdd(&sh[NBKT + (s.w >> 8)], 1);
    }
    __syncthreads();
    for (int k = t; k < 2 * NBKT; k += 256) gcnt[k * NBP1 + cb] = sh[k];
}

// ---------------- GEMM1: deep-staged bf16 LDS tile + MFMA ---------------------
__global__ __launch_bounds__(256) void k_gemm1(const float* __restrict__ X,
                                               const unsigned short* __restrict__ Bp,
                                               const float* __restrict__ nsrcf,
                                               unsigned short* __restrict__ h1b) {
    __shared__ unsigned short xt[64 * 256];   // 32 KB bf16 tile (XOR-swizzled)
    const int bid = blockIdx.x, t = threadIdx.x;
    const int r0 = bid * 64;

    f32x4 v[16];
    #pragma unroll
    for (int q = 0; q < 16; ++q) {
        const int idx = q * 1024 + t * 4;             // element index in 64x256 tile
        const int row = idx >> 8, col = idx & 255;
        const int gr  = (r0 + row < NN) ? (r0 + row) : (NN - 1);   // tail clamp
        v[q] = *reinterpret_cast<const f32x4*>(X + (size_t)gr * IN_F + col);
    }
    __builtin_amdgcn_sched_barrier(0);                // keep all 16 in flight
    #pragma unroll
    for (int q = 0; q < 16; ++q) {
        const int idx = q * 1024 + t * 4;
        const int row = idx >> 8, col = idx & 255;
        const unsigned int w0 = (unsigned)f2bf(v[q][0]) | ((unsigned)f2bf(v[q][1]) << 16);
        const unsigned int w1 = (unsigned)f2bf(v[q][2]) | ((unsigned)f2bf(v[q][3]) << 16);
        const int a = ((row * 256 + col) * 2) ^ ((row & 7) << 4);  // byte addr, swizzled
        uint2 pk; pk.x = w0; pk.y = w1;
        *reinterpret_cast<uint2*>(reinterpret_cast<char*>(xt) + a) = pk;
    }
    __syncthreads();
    const int lane = t & 63;
    const int wid  = t >> 6;
    const int rloc = wid * 16 + (lane & 15);          // local row 0..63
    const bf16x8* bp = reinterpret_cast<const bf16x8*>(Bp) + lane;

    f32x4 acc0 = {0.f, 0.f, 0.f, 0.f};
    f32x4 acc1 = {0.f, 0.f, 0.f, 0.f};
    f32x4 acc2 = {0.f, 0.f, 0.f, 0.f};
    f32x4 acc3 = {0.f, 0.f, 0.f, 0.f};

    #pragma unroll
    for (int kt = 0; kt < 8; ++kt) {
        const int koff = (lane >> 4) * 8 + kt * 32;
        const int a = ((rloc * 256 + koff) * 2) ^ ((rloc & 7) << 4);
        const bf16x8 av = *reinterpret_cast<const bf16x8*>(
                              reinterpret_cast<char*>(xt) + a);
        const bf16x8 b0 = bp[(kt * 4 + 0) * 64];
        const bf16x8 b1 = bp[(kt * 4 + 1) * 64];
        const bf16x8 b2 = bp[(kt * 4 + 2) * 64];
        const bf16x8 b3 = bp[(kt * 4 + 3) * 64];
        acc0 = __builtin_amdgcn_mfma_f32_16x16x32_bf16(av, b0, acc0, 0, 0, 0);
        acc1 = __builtin_amdgcn_mfma_f32_16x16x32_bf16(av, b1, acc1, 0, 0, 0);
        acc2 = __builtin_amdgcn_mfma_f32_16x16x32_bf16(av, b2, acc2, 0, 0, 0);
        acc3 = __builtin_amdgcn_mfma_f32_16x16x32_bf16(av, b3, acc3, 0, 0, 0);
    }

    // C/D layout: col = lane&15, row = (lane>>4)*4 + reg   [m89-verified]
    const int crow = r0 + wid * 16 + (lane >> 4) * 4;
    const int ccol = lane & 15;
    #pragma unroll
    for (int rr = 0; rr < 4; ++rr) {
        const int orow = crow + rr;
        if (orow < NN) {
            const float ns = nsrcf[orow];
            unsigned short* o = h1b + (size_t)orow * HID + ccol;
            o[0]  = f2bf(acc0[rr] * ns);
            o[16] = f2bf(acc1[rr] * ns);
            o[32] = f2bf(acc2[rr] * ns);
            o[48] = f2bf(acc3[rr] * ns);
        }
    }
}

// ---------------- scan A: per-row total = sum over blocks --------------------
__global__ __launch_bounds__(256) void k_scanA(const int* __restrict__ gcnt,
                                               int* __restrict__ bsum) {
    __shared__ int red[256];
    const int r = blockIdx.x, t = threadIdx.x;
    int x = gcnt[r * NBP1 + t];
    if (256 + t < NBP1) x += gcnt[r * NBP1 + 256 + t];
    red[t] = x;
    __syncthreads();
    for (int off = 128; off > 0; off >>= 1) {
        if (t < off) red[t] += red[t + off];
        __syncthreads();
    }
    if (t == 0) bsum[r] = red[0];
}

// ---------------- scan B: per-array exclusive scan -> bstart[a][0..NBKT] ------
__global__ __launch_bounds__(512) void k_scanB(const int* __restrict__ bsum,
                                               int* __restrict__ bstart) {
    __shared__ int sa[512], sb[512];
    const int a = blockIdx.x, t = threadIdx.x;       // a in {0,1}
    const int x = (t < NBKT) ? bsum[a * NBKT + t] : 0;
    sa[t] = x;
    __syncthreads();
    int* pin = sa; int* pout = sb;
    for (int off = 1; off < 512; off <<= 1) {
        int v = pin[t];
        if (t >= off) v += pin[t - off];
        pout[t] = v;
        __syncthreads();
        int* tmp = pin; pin = pout; pout = tmp;
    }
    if (t <= NBKT) bstart[a * (NBKT + 1) + t] = pin[t] - x;   // exclusive
}

// ---------------- scan C: per-row exclusive scan -> segment bases (in place) --
__global__ __launch_bounds__(512) void k_scanC(int* __restrict__ gcnt,
                                               const int* __restrict__ bstart) {
    __shared__ int sa[512], sb[512];
    const int r = blockIdx.x, t = threadIdx.x;
    const int a = r / NBKT;                           // bstart row offset: r + a
    const int x = (t < NBP1) ? gcnt[r * NBP1 + t] : 0;
    sa[t] = x;
    __syncthreads();
    int* pin = sa; int* pout = sb;
    for (int off = 1; off < 512; off <<= 1) {
        int v = pin[t];
        if (t >= off) v += pin[t - off];
        pout[t] = v;
        __syncthreads();
        int* tmp = pin; pin = pout; pout = tmp;
    }
    if (t < NBP1) gcnt[r * NBP1 + t] = bstart[r + a] + pin[t] - x;
}

// ---------------- partition pass b: scatter into dst- AND src-bucket segments -
__global__ __launch_bounds__(256) void k_scatter(const int* __restrict__ src,
                                                 const int* __restrict__ dst,
                                                 const int* __restrict__ gbase,
                                                 int* __restrict__ pedge,
                                                 unsigned char* __restrict__ psrc) {
    __shared__ int cur[2 * NBKT];
    const int b = blockIdx.x, t = threadIdx.x;
    for (int k = t; k < 2 * NBKT; k += 256) cur[k] = gbase[k * NBP1 + b];
    __syncthreads();
    const int4* s4 = reinterpret_cast<const int4*>(src) + (size_t)b * EI4;
    const int4* d4 = reinterpret_cast<const int4*>(dst) + (size_t)b * EI4;
    for (int i = t; i < EI4; i += 256) {
        const int4 dd = d4[i], ss = s4[i];
        {
            const int posD = atomicAdd(&cur[dd.x >> 8], 1);
            pedge[posD] = ss.x | ((dd.x & 255) << 17);
            const int posS = atomicAdd(&cur[NBKT + (ss.x >> 8)], 1);
            psrc[posS] = (unsigned char)(ss.x & 255);
        }
        {
            const int posD = atomicAdd(&cur[dd.y >> 8], 1);
            pedge[posD] = ss.y | ((dd.y & 255) << 17);
            const int posS = atomicAdd(&cur[NBKT + (ss.y >> 8)], 1);
            psrc[posS] = (unsigned char)(ss.y & 255);
        }
        {
            const int posD = atomicAdd(&cur[dd.z >> 8], 1);
            pedge[posD] = ss.z | ((dd.z & 255) << 17);
            const int posS = atomicAdd(&cur[NBKT + (ss.z >> 8)], 1);
            psrc[posS] = (unsigned char)(ss.z & 255);
        }
        {
            const int posD = atomicAdd(&cur[dd.w >> 8], 1);
            pedge[posD] = ss.w | ((dd.w & 255) << 17);
            const int posS = atomicAdd(&cur[NBKT + (ss.w >> 8)], 1);
            psrc[posS] = (unsigned char)(ss.w & 255);
        }
    }
}

// ---------------- place (merged D+S): CSR slots + ideg | src counts -> nsrcf --
__global__ __launch_bounds__(256) void k_place(const int* __restrict__ pedge,
                                               const unsigned char* __restrict__ psrc,
                                               const int* __restrict__ bstart,
                                               int* __restrict__ eidx,
                                               int* __restrict__ ideg,
                                               float* __restrict__ nsrcf) {
    __shared__ int cnt[256];
    const int kk = blockIdx.x, t = threadIdx.x;
    cnt[t] = 0;
    __syncthreads();
    if (kk < NBKT) {
        const int k  = kk;
        const int i0 = bstart[k], i1 = bstart[k + 1];
        for (int i = i0 + t; i < i1; i += 256) {
            const int v  = pedge[i];
            const int s  = v & 0x1FFFF;
            const int lo = v >> 17;
            const int c  = atomicAdd(&cnt[lo], 1);            // LDS atomic
            if (c < CAP) eidx[(size_t)((k << 8) | lo) * CAP + c] = s;
        }
        __syncthreads();
        const int d = (k << 8) | t;
        if (d < NN) ideg[d] = cnt[t];
    } else {
        const int k  = kk - NBKT;
        const int* bs = bstart + (NBKT + 1);
        const int i0 = bs[k], i1 = bs[k + 1];
        for (int i = i0 + t; i < i1; i += 256)
            atomicAdd(&cnt[psrc[i]], 1);                      // LDS atomic
        __syncthreads();
        const int d = (k << 8) | t;
        if (d < NN) nsrcf[d] = rsqrtf(fmaxf((float)cnt[t], 1.f));
    }
}

// ---------------- aggregation, 64 feats: 4 edges per gather instruction -------
// r12: lane L -> edge-slot group g=L>>4, feature-quad fl=L&15 (dwordx2, 8B).
// 16 lanes span a 128B row => one wave64 instruction fetches FOUR rows (r7's
// pair form fetched two). Slot ids come from 4 uniform readlanes + 2 per-lane
// cndmask selects. Tail: <=4 single-gather iterations, clamping only inside
// the final partial group (r11's round-to-16 added ~8 clamped loads/node and
// regressed; this adds ~1.7).
__global__ __launch_bounds__(256) void k_agg64(const int* __restrict__ eidx,
                                               const int* __restrict__ ideg,
                                               const unsigned short* __restrict__ h1b,
                                               const float* __restrict__ b1,
                                               float* __restrict__ hout) {
    const int w    = (blockIdx.x * 256 + threadIdx.x) >> 6;
    const int lane = threadIdx.x & 63;
    if (w >= NN) return;
    const int cnt  = ideg[w];
    const int m    = cnt < CAP ? cnt : CAP;
    const int idxv = eidx[(size_t)w * CAP + lane];   // slots >= m: garbage, never read
    const int g    = lane >> 4;                      // edge-slot group 0..3
    const unsigned fofs = (unsigned)(lane & 15) * 8u;   // feature-quad byte offset
    const char* hb = reinterpret_cast<const char*>(h1b);
    float ax = 0.f, ay = 0.f, az = 0.f, aw = 0.f;

    #define G4_64(J0, OUT)                                                    \
        {                                                                     \
            const int s0 = __builtin_amdgcn_readlane(idxv, (J0));             \
            const int s1 = __builtin_amdgcn_readlane(idxv, (J0) + 1);         \
            const int s2 = __builtin_amdgcn_readlane(idxv, (J0) + 2);         \
            const int s3 = __builtin_amdgcn_readlane(idxv, (J0) + 3);         \
            const int slo = (lane & 16) ? s1 : s0;                            \
            const int shi = (lane & 16) ? s3 : s2;                            \
            const int s   = (lane & 32) ? shi : slo;                          \
            OUT = *reinterpret_cast<const uint2*>(hb + (unsigned)s * 128u + fofs); \
        }

    int j = 0;
    for (; j + 16 <= m; j += 16) {                   // 16 edges = 4 gathers in flight
        uint2 q0, q1, q2, q3;
        G4_64(j + 0,  q0); G4_64(j + 4,  q1); G4_64(j + 8,  q2); G4_64(j + 12, q3);
        ax += bf2f((unsigned short)(q0.x & 0xffffu)) + bf2f((unsigned short)(q1.x & 0xffffu))
            + bf2f((unsigned short)(q2.x & 0xffffu)) + bf2f((unsigned short)(q3.x & 0xffffu));
        ay += bf2f((unsigned short)(q0.x >> 16)) + bf2f((unsigned short)(q1.x >> 16))
            + bf2f((unsigned short)(q2.x >> 16)) + bf2f((unsigned short)(q3.x >> 16));
        az += bf2f((unsigned short)(q0.y & 0xffffu)) + bf2f((unsigned short)(q1.y & 0xffffu))
            + bf2f((unsigned short)(q2.y & 0xffffu)) + bf2f((unsigned short)(q3.y & 0xffffu));
        aw += bf2f((unsigned short)(q0.y >> 16)) + bf2f((unsigned short)(q1.y >> 16))
            + bf2f((unsigned short)(q2.y >> 16)) + bf2f((unsigned short)(q3.y >> 16));
    }
    for (; j < m; j += 4) {                          // <=4 iters; clamp final group only
        const int c1 = (j + 1 < m) ? j + 1 : m - 1;
        const int c2 = (j + 2 < m) ? j + 2 : m - 1;
        const int c3 = (j + 3 < m) ? j + 3 : m - 1;
        const int s0 = __builtin_amdgcn_readlane(idxv, j);
        const int s1 = __builtin_amdgcn_readlane(idxv, c1);
        const int s2 = __builtin_amdgcn_readlane(idxv, c2);
        const int s3 = __builtin_amdgcn_readlane(idxv, c3);
        const int slo = (lane & 16) ? s1 : s0;
        const int shi = (lane & 16) ? s3 : s2;
        const int s   = (lane & 32) ? shi : slo;
        const uint2 v = *reinterpret_cast<const uint2*>(hb + (unsigned)s * 128u + fofs);
        const float mk = (j + g < m) ? 1.f : 0.f;
        ax = fmaf(bf2f((unsigned short)(v.x & 0xffffu)), mk, ax);
        ay = fmaf(bf2f((unsigned short)(v.x >> 16)), mk, ay);
        az = fmaf(bf2f((unsigned short)(v.y & 0xffffu)), mk, az);
        aw = fmaf(bf2f((unsigned short)(v.y >> 16)), mk, aw);
    }
    #undef G4_64
    ax += __shfl(ax, lane ^ 16); ax += __shfl(ax, lane ^ 32);
    ay += __shfl(ay, lane ^ 16); ay += __shfl(ay, lane ^ 32);
    az += __shfl(az, lane ^ 16); az += __shfl(az, lane ^ 32);
    aw += __shfl(aw, lane ^ 16); aw += __shfl(aw, lane ^ 32);
    if (lane < 16) {
        const float nd = rsqrtf(fmaxf((float)cnt, 1.f));
        const f32x4 bb = *reinterpret_cast<const f32x4*>(b1 + lane * 4);
        f32x4 o;
        o[0] = fmaf(ax, nd, bb[0]);
        o[1] = fmaf(ay, nd, bb[1]);
        o[2] = fmaf(az, nd, bb[2]);
        o[3] = fmaf(aw, nd, bb[3]);
        *reinterpret_cast<f32x4*>(hout + (size_t)w * HID + lane * 4) = o;
    }
}

// ---------------- layer 2 GEMM via MFMA: relu(h) @ W2 -------------------------
__global__ __launch_bounds__(256) void k_gemm2(const float* __restrict__ h,
                                               const unsigned short* __restrict__ Bp2,
                                               const float* __restrict__ nsrcf,
                                               unsigned short* __restrict__ xwb) {
    const int t = threadIdx.x;
    const int lane = t & 63;
    const int wid  = t >> 6;
    const int r0w  = blockIdx.x * 64 + wid * 16;
    if (r0w >= NN) return;                            // NN % 16 == 0: no row tail
    const int row = r0w + (lane & 15);
    const float* hr = h + (size_t)row * HID + (lane >> 4) * 8;
    const bf16x8* bp = reinterpret_cast<const bf16x8*>(Bp2) + lane;

    f32x4 acc0 = {0.f, 0.f, 0.f, 0.f};
    f32x4 acc1 = {0.f, 0.f, 0.f, 0.f};
    f32x4 acc2 = {0.f, 0.f, 0.f, 0.f};
    #pragma unroll
    for (int kt = 0; kt < 2; ++kt) {
        const f32x4 v0 = *reinterpret_cast<const f32x4*>(hr + kt * 32);
        const f32x4 v1 = *reinterpret_cast<const f32x4*>(hr + kt * 32 + 4);
        bf16x8 a;
        a[0] = (short)f2bf(fmaxf(v0[0], 0.f));
        a[1] = (short)f2bf(fmaxf(v0[1], 0.f));
        a[2] = (short)f2bf(fmaxf(v0[2], 0.f));
        a[3] = (short)f2bf(fmaxf(v0[3], 0.f));
        a[4] = (short)f2bf(fmaxf(v1[0], 0.f));
        a[5] = (short)f2bf(fmaxf(v1[1], 0.f));
        a[6] = (short)f2bf(fmaxf(v1[2], 0.f));
        a[7] = (short)f2bf(fmaxf(v1[3], 0.f));
        const bf16x8 b0 = bp[(kt * 3 + 0) * 64];
        const bf16x8 b1 = bp[(kt * 3 + 1) * 64];
        const bf16x8 b2 = bp[(kt * 3 + 2) * 64];
        acc0 = __builtin_amdgcn_mfma_f32_16x16x32_bf16(a, b0, acc0, 0, 0, 0);
        acc1 = __builtin_amdgcn_mfma_f32_16x16x32_bf16(a, b1, acc1, 0, 0, 0);
        acc2 = __builtin_amdgcn_mfma_f32_16x16x32_bf16(a, b2, acc2, 0, 0, 0);
    }
    // C/D layout: col = lane&15, row = (lane>>4)*4 + reg
    const int crow = r0w + (lane >> 4) * 4;
    const int ccol = lane & 15;
    #pragma unroll
    for (int rr = 0; rr < 4; ++rr) {
        const int orow = crow + rr;
        const float ns = nsrcf[orow];
        unsigned short* o = xwb + (size_t)orow * 64 + ccol;
        o[0]  = f2bf(acc0[rr] * ns);
        o[16] = f2bf(acc1[rr] * ns);
        o[32] = f2bf(acc2[rr] * ns);                  // cols 40-47: 0 (zero B-frag)
        o[48] = 0;                                    // pad cols 48-63
    }
}

// ---------------- aggregation, 40 feats: 4 edges per gather instruction -------
// Same structure as k_agg64; xwb rows are 128B padded (cols 40-63 = 0), so all
// 16 feature-quads are readable and pads contribute exact zeros.
__global__ __launch_bounds__(256) void k_agg40(const int* __restrict__ eidx,
                                               const int* __restrict__ ideg,
                                               const unsigned short* __restrict__ xwb,
                                               const float* __restrict__ b2,
                                               float* __restrict__ out) {
    const int w    = (blockIdx.x * 256 + threadIdx.x) >> 6;
    const int lane = threadIdx.x & 63;
    if (w >= NN) return;
    const int cnt  = ideg[w];
    const int m    = cnt < CAP ? cnt : CAP;
    const int idxv = eidx[(size_t)w * CAP + lane];
    const int g    = lane >> 4;
    const unsigned fofs = (unsigned)(lane & 15) * 8u;
    const char* xb = reinterpret_cast<const char*>(xwb);
    float ax = 0.f, ay = 0.f, az = 0.f, aw = 0.f;

    #define G4_40(J0, OUT)                                                    \
        {                                                                     \
            const int s0 = __builtin_amdgcn_readlane(idxv, (J0));             \
            const int s1 = __builtin_amdgcn_readlane(idxv, (J0) + 1);         \
            const int s2 = __builtin_amdgcn_readlane(idxv, (J0) + 2);         \
            const int s3 = __builtin_amdgcn_readlane(idxv, (J0) + 3);         \
            const int slo = (lane & 16) ? s1 : s0;                            \
            const int shi = (lane & 16) ? s3 : s2;                            \
            const int s   = (lane & 32) ? shi : slo;                          \
            OUT = *reinterpret_cast<const uint2*>(xb + (unsigned)s * 128u + fofs); \
        }

    int j = 0;
    for (; j + 16 <= m; j += 16) {
        uint2 q0, q1, q2, q3;
        G4_40(j + 0,  q0); G4_40(j + 4,  q1); G4_40(j + 8,  q2); G4_40(j + 12, q3);
        ax += bf2f((unsigned short)(q0.x & 0xffffu)) + bf2f((unsigned short)(q1.x & 0xffffu))
            + bf2f((unsigned short)(q2.x & 0xffffu)) + bf2f((unsigned short)(q3.x & 0xffffu));
        ay += bf2f((unsigned short)(q0.x >> 16)) + bf2f((unsigned short)(q1.x >> 16))
            + bf2f((unsigned short)(q2.x >> 16)) + bf2f((unsigned short)(q3.x >> 16));
        az += bf2f((unsigned short)(q0.y & 0xffffu)) + bf2f((unsigned short)(q1.y & 0xffffu))
            + bf2f((unsigned short)(q2.y & 0xffffu)) + bf2f((unsigned short)(q3.y & 0xffffu));
        aw += bf2f((unsigned short)(q0.y >> 16)) + bf2f((unsigned short)(q1.y >> 16))
            + bf2f((unsigned short)(q2.y >> 16)) + bf2f((unsigned short)(q3.y >> 16));
    }
    for (; j < m; j += 4) {
        const int c1 = (j + 1 < m) ? j + 1 : m - 1;
        const int c2 = (j + 2 < m) ? j + 2 : m - 1;
        const int c3 = (j + 3 < m) ? j + 3 : m - 1;
        const int s0 = __builtin_amdgcn_readlane(idxv, j);
        const int s1 = __builtin_amdgcn_readlane(idxv, c1);
        const int s2 = __builtin_amdgcn_readlane(idxv, c2);
        const int s3 = __builtin_amdgcn_readlane(idxv, c3);
        const int slo = (lane & 16) ? s1 : s0;
        const int shi = (lane & 16) ? s3 : s2;
        const int s   = (lane & 32) ? shi : slo;
        const uint2 v = *reinterpret_cast<const uint2*>(xb + (unsigned)s * 128u + fofs);
        const float mk = (j + g < m) ? 1.f : 0.f;
        ax = fmaf(bf2f((unsigned short)(v.x & 0xffffu)), mk, ax);
        ay = fmaf(bf2f((unsigned short)(v.x >> 16)), mk, ay);
        az = fmaf(bf2f((unsigned short)(v.y & 0xffffu)), mk, az);
        aw = fmaf(bf2f((unsigned short)(v.y >> 16)), mk, aw);
    }
    #undef G4_40
    ax += __shfl(ax, lane ^ 16); ax += __shfl(ax, lane ^ 32);
    ay += __shfl(ay, lane ^ 16); ay += __shfl(ay, lane ^ 32);
    az += __shfl(az, lane ^ 16); az += __shfl(az, lane ^ 32);
    aw += __shfl(aw, lane ^ 16); aw += __shfl(aw, lane ^ 32);
    if (lane < 10) {                                 // 10 quads = 40 cols
        const float nd = rsqrtf(fmaxf((float)cnt, 1.f));
        const f32x4 bb = *reinterpret_cast<const f32x4*>(b2 + lane * 4);
        f32x4 o;
        o[0] = fmaf(ax, nd, bb[0]);
        o[1] = fmaf(ay, nd, bb[1]);
        o[2] = fmaf(az, nd, bb[2]);
        o[3] = fmaf(aw, nd, bb[3]);
        *reinterpret_cast<f32x4*>(out + (size_t)w * NC + lane * 4) = o;
    }
}

extern "C" void kernel_launch(void* const* d_in, const int* in_sizes, int n_in,
                              void* d_out, int out_size, void* d_ws, size_t ws_size,
                              hipStream_t stream) {
    const float* X   = (const float*)d_in[0];
    const int*   src = (const int*)d_in[1];
    const int*   dst = (const int*)d_in[2];
    const float* W1  = (const float*)d_in[3];
    const float* b1  = (const float*)d_in[4];
    const float* W2  = (const float*)d_in[5];
    const float* b2  = (const float*)d_in[6];

    float* out  = (float*)d_out;
    float* xout = out;                          // [NN*NC] final layer-2 output
    float* hout = out + (size_t)NN * NC;        // [NN*HID] layer-1 output h

    // ---- scratch living in d_out (liveness-checked):
    // gcnt/bsum/bstart in xout region (~1.6MB of 16MB): dead before k_agg40 writes xout.
    // pedge+psrc in hout region (8MB of 25.6MB): dead before k_agg64 writes hout.
    int* gcnt   = (int*)xout;                   // [2*NBKT*NBP1] counts -> bases (in-place)
    int* bsum   = gcnt + 2 * NBKT * NBP1;       // [2*NBKT]
    int* bstart = bsum + 2 * NBKT;              // [2*(NBKT+1)]
    int* pedge  = (int*)hout;                   // [NE] packed (src | dlow<<17)
    unsigned char* psrc = (unsigned char*)(pedge + NE);   // [NE] low byte of src

    // ---- workspace layout ----
    char* ws = (char*)d_ws;
    int* ideg  = (int*)ws;                            ws += sizeof(int) * NN;
    int* eidx  = (int*)ws;                            ws += sizeof(int) * (size_t)NN * CAP;
    unsigned short* Bp  = (unsigned short*)ws;        ws += sizeof(unsigned short) * 8 * 4 * 64 * 8;
    unsigned short* Bp2 = (unsigned short*)ws;        ws += sizeof(unsigned short) * 6 * 64 * 8;
    float* nsrcf = (float*)ws;                        ws += sizeof(float) * NN;
    unsigned short* h1b = (unsigned short*)ws;        // [NN*HID] bf16, 12.8 MB
    unsigned short* xwb = h1b;                        // reuse: [NN*64] padded, same 12.8 MB

    // sort pipeline first (produces nsrcf for gemm1's pre-scaled epilogue)
    k_count  <<<NBP1 + 10, 256, 0, stream>>>(src, dst, W1, W2, Bp, Bp2, gcnt);
    k_scanA  <<<2 * NBKT, 256, 0, stream>>>(gcnt, bsum);
    k_scanB  <<<2, 512, 0, stream>>>(bsum, bstart);
    k_scanC  <<<2 * NBKT, 512, 0, stream>>>(gcnt, bstart);
    k_scatter<<<NBP1, 256, 0, stream>>>(src, dst, gcnt, pedge, psrc);
    k_place  <<<2 * NBKT, 256, 0, stream>>>(pedge, psrc, bstart, eidx, ideg, nsrcf);
    k_gemm1  <<<NB_GEMM, 256, 0, stream>>>(X, Bp, nsrcf, h1b);
    k_agg64  <<<(NN * 64 + 255) / 256, 256, 0, stream>>>(eidx, ideg, h1b, b1, hout);
    k_gemm2  <<<NB_GEMM, 256, 0, stream>>>(hout, Bp2, nsrcf, xwb);
    k_agg40  <<<(NN * 64 + 255) / 256, 256, 0, stream>>>(eidx, ideg, xwb, b2, xout);
}